// Round 10
// baseline (33.783 us; speedup 1.0000x reference)
//
#include <hip/hip_runtime.h>

// RangeLoss: out = sum_i[(p-t_adj)^2 + (log p - log t_adj)^2] / N^2
// t_adj = p if (p*1.05 > t && p*0.95 < t) else t.  N = 2^24 -> scale = 2^-48.
//
// FINAL FORM (R10 = R2 revert, best measured: 31.79us).
// Session findings:
//  - Two-kernel (2048-block partial + 1-block final) beats every fused
//    variant: fences emit per-XCD L2 writeback/inv (3x slowdown, R4);
//    fence-free spin finale still loses ~2us to the graph edge (R9).
//  - Main loop is at the practical read-reduce ceiling ~4.9 TB/s (matches
//    m146's 4.89 TB/s): 1x/4x/nt load variants all 31.8 +/- 0.1us.
//  - FETCH pinned at 65.5MB: harness's 268MB inter-replay fills control L3
//    residency; nt-loads (no L3 alloc) HURT (+2.6us) by killing next-replay
//    L3 hits.
// Floor arithmetic: 128MiB / 4.9TB/s ~= 27.4us + ~4us final/launch ~= 31us.

typedef float f32x4 __attribute__((ext_vector_type(4)));

constexpr int RL_THREADS = 256;
constexpr int RL_BLOCKS  = 2048;   // 8 blocks/CU, one resident generation
constexpr int RL_UNROLL  = 4;      // independent float4 pairs in flight

__global__ __launch_bounds__(RL_THREADS) void rangeloss_partial(
    const float* __restrict__ preds, const float* __restrict__ target,
    float* __restrict__ partials, int n) {
  const int tid    = blockIdx.x * RL_THREADS + threadIdx.x;
  const int stride = RL_BLOCKS * RL_THREADS;          // in float4 units
  const int n4     = n >> 2;
  const f32x4* __restrict__ p4 = reinterpret_cast<const f32x4*>(preds);
  const f32x4* __restrict__ t4 = reinterpret_cast<const f32x4*>(target);

  float acc = 0.0f;

  // Guarded-outer, unguarded-inner unroll (no divisibility requirement,
  // no per-u branches -> 8 loads batched in flight; VGPR ~36).
  int base = tid;
  for (; base + (RL_UNROLL - 1) * stride < n4; base += RL_UNROLL * stride) {
    f32x4 p[RL_UNROLL], t[RL_UNROLL];
    #pragma unroll
    for (int u = 0; u < RL_UNROLL; ++u) p[u] = p4[base + u * stride];
    #pragma unroll
    for (int u = 0; u < RL_UNROLL; ++u) t[u] = t4[base + u * stride];

    #pragma unroll
    for (int u = 0; u < RL_UNROLL; ++u) {
      #pragma unroll
      for (int j = 0; j < 4; ++j) {
        float pj = p[u][j];
        float tj = t[u][j];
        bool in_range = (pj * 1.05f > tj) && (pj * 0.95f < tj);
        float ta = in_range ? pj : tj;
        float d  = pj - ta;                     // 0 when in_range
        float ld = __logf(pj) - __logf(ta);     // 0 when in_range
        acc += d * d + ld * ld;
      }
    }
  }
  // Tail (unused for N=2^24; kept for generality).
  for (; base < n4; base += stride) {
    f32x4 p = p4[base];
    f32x4 t = t4[base];
    #pragma unroll
    for (int j = 0; j < 4; ++j) {
      float pj = p[j];
      float tj = t[j];
      bool in_range = (pj * 1.05f > tj) && (pj * 0.95f < tj);
      float ta = in_range ? pj : tj;
      float d  = pj - ta;
      float ld = __logf(pj) - __logf(ta);
      acc += d * d + ld * ld;
    }
  }

  // wave(64) shuffle reduce
  #pragma unroll
  for (int off = 32; off > 0; off >>= 1) acc += __shfl_down(acc, off, 64);

  __shared__ float smem[RL_THREADS / 64];
  const int lane = threadIdx.x & 63;
  const int wid  = threadIdx.x >> 6;
  if (lane == 0) smem[wid] = acc;
  __syncthreads();
  if (threadIdx.x == 0) {
    float s = 0.0f;
    #pragma unroll
    for (int w = 0; w < RL_THREADS / 64; ++w) s += smem[w];
    partials[blockIdx.x] = s;
  }
}

__global__ __launch_bounds__(RL_THREADS) void rangeloss_final(
    const float* __restrict__ partials, float* __restrict__ out, float scale) {
  float acc = 0.0f;
  for (int i = threadIdx.x; i < RL_BLOCKS; i += RL_THREADS) acc += partials[i];
  #pragma unroll
  for (int off = 32; off > 0; off >>= 1) acc += __shfl_down(acc, off, 64);

  __shared__ float smem[RL_THREADS / 64];
  const int lane = threadIdx.x & 63;
  const int wid  = threadIdx.x >> 6;
  if (lane == 0) smem[wid] = acc;
  __syncthreads();
  if (threadIdx.x == 0) {
    float s = 0.0f;
    #pragma unroll
    for (int w = 0; w < RL_THREADS / 64; ++w) s += smem[w];
    out[0] = s * scale;
  }
}

extern "C" void kernel_launch(void* const* d_in, const int* in_sizes, int n_in,
                              void* d_out, int out_size, void* d_ws, size_t ws_size,
                              hipStream_t stream) {
  const float* preds  = (const float*)d_in[0];
  const float* target = (const float*)d_in[1];
  float* out      = (float*)d_out;
  float* partials = (float*)d_ws;          // RL_BLOCKS floats = 8 KiB
  const int n = in_sizes[0];

  // loss = sum / (n * n); n = 2^24 -> exact 2^-48
  const float scale = (float)(1.0 / ((double)n * (double)n));

  rangeloss_partial<<<RL_BLOCKS, RL_THREADS, 0, stream>>>(preds, target, partials, n);
  rangeloss_final<<<1, RL_THREADS, 0, stream>>>(partials, out, scale);
}